// Round 1
// baseline (2450.864 us; speedup 1.0000x reference)
//
#include <hip/hip_runtime.h>
#include <stdint.h>

#define T_ 512
#define B_ 64
#define H_ 512
#define L_ 2
#define TBH (T_*B_*H_)   // 16777216
#define BH  (B_*H_)      // 32768
#define NC  8            // time chunks
#define CS  64           // steps per chunk
#define CROWS (CS*B_)    // 4096 rows of [T*B] per chunk
#define CSZ ((size_t)CROWS*H_)     // floats per chunk slot (8 MiB)
#define WPK_OFF ((size_t)4*CSZ)    // ws float-offset of packed streamed weights
#define WPK_U4L (16*512)           // uint4 per layer of packed streamed weights

typedef float    f32x4 __attribute__((ext_vector_type(4)));
typedef short    s16x8 __attribute__((ext_vector_type(8)));
typedef short    s16x4 __attribute__((ext_vector_type(4)));
typedef _Float16 h2    __attribute__((ext_vector_type(2)));

static __device__ __forceinline__ short f2bf(float f) {
  uint32_t u = __float_as_uint(f);
  u = (u + 0x7fffu + ((u >> 16) & 1u)) >> 16;  // RNE
  return (short)u;
}

static __device__ __forceinline__ float fdot2(h2 a, h2 b, float c) {
#if __has_builtin(__builtin_amdgcn_fdot2)
  return __builtin_amdgcn_fdot2(a, b, c, false);
#else
  return c + (float)a[0] * (float)b[0] + (float)a[1] * (float)b[1];
#endif
}

template <int IMM>
static __device__ __forceinline__ float swz(float v) {
  return __int_as_float(__builtin_amdgcn_ds_swizzle(__float_as_int(v), IMM));
}

// DPP quad_perm cross-lane (VALU pipe, replaces ds_swizzle for xor1/xor2)
static __device__ __forceinline__ float dpp_xor1(float v) {
  return __int_as_float(__builtin_amdgcn_mov_dpp(__float_as_int(v), 0xB1, 0xF, 0xF, true));
}
static __device__ __forceinline__ float dpp_xor2(float v) {
  return __int_as_float(__builtin_amdgcn_mov_dpp(__float_as_int(v), 0x4E, 0xF, 0xF, true));
}

static __device__ __forceinline__ uint32_t pack2(float a, float b) {
  h2 p = { (_Float16)a, (_Float16)b };
  return __builtin_bit_cast(uint32_t, p);
}

static __device__ __forceinline__ h2 bch(uint32_t u) {
  return __builtin_bit_cast(h2, u);
}

// ---------------------------------------------------------------------------
// One-time pre-pack: cols 48..63 of each thread's 64-col slice of Whh, fp16,
// laid out exactly as the old wlds LDS layout: dst[(k*2+p)*512 + tid].
// 128 KiB per layer -> L2-resident, streamed per step via VMEM.
// ---------------------------------------------------------------------------
__global__ __launch_bounds__(512, 1)
void prepack(const float* __restrict__ Whh, float* __restrict__ ws) {
  const int l = blockIdx.x;       // 2 blocks = 2 layers
  const int tid = threadIdx.x;
  const int c = tid & 7, rg = tid >> 3;
  uint4* dst = (uint4*)(ws + WPK_OFF) + (size_t)l * WPK_U4L;
  const float* W = Whh + (size_t)l * H_ * H_;
  #pragma unroll
  for (int k = 0; k < 8; ++k) {
    const float* wrow = W + (size_t)(rg * 8 + k) * H_ + c * 64;
    #pragma unroll
    for (int p = 0; p < 2; ++p) {
      f32x4 w4 = *(const f32x4*)(wrow + 48 + p * 8);
      f32x4 w5 = *(const f32x4*)(wrow + 48 + p * 8 + 4);
      uint4 pk;
      pk.x = pack2(w4.x, w4.y);
      pk.y = pack2(w4.z, w4.w);
      pk.z = pack2(w5.x, w5.y);
      pk.w = pack2(w5.z, w5.w);
      dst[(k * 2 + p) * 512 + tid] = pk;
    }
  }
}

// ---------------------------------------------------------------------------
// GEMM role (unchanged): 512 threads, 256x128 tile, 8 waves as 4Mx2N of 64x64.
// ---------------------------------------------------------------------------
__device__ void gemm_role(char* smem, int rb,
                          const float* __restrict__ In,
                          const float* __restrict__ W,
                          const float* __restrict__ bi,
                          const float* __restrict__ bh,
                          float* __restrict__ Out) {
  constexpr int LDT = 40;
  short* As = (short*)smem;              // 256 x LDT
  short* Bs = (short*)(smem + 256 * LDT * 2);  // 128 x LDT

  const int tid  = threadIdx.x;
  const int m0   = (rb >> 2) * 256;
  const int n0   = (rb & 3) * 128;
  const int wave = tid >> 6, lane = tid & 63;
  const int wm   = (wave >> 1) * 64;
  const int wn   = (wave & 1) * 64;
  const int quad = lane >> 4, tq = lane & 15;

  f32x4 acc[4][4] = {};

  for (int k0 = 0; k0 < 512; k0 += 32) {
    #pragma unroll
    for (int v = 0; v < 4; ++v) {
      int idx = v * 512 + tid;
      int r = idx >> 3, cc = (idx & 7) * 4;
      f32x4 a = *(const f32x4*)(In + (size_t)(m0 + r) * 512 + k0 + cc);
      s16x4 ap = { f2bf(a.x), f2bf(a.y), f2bf(a.z), f2bf(a.w) };
      *(s16x4*)(&As[r * LDT + cc]) = ap;
    }
    #pragma unroll
    for (int v = 0; v < 2; ++v) {
      int idx = v * 512 + tid;
      int r = idx >> 3, cc = (idx & 7) * 4;
      f32x4 b = *(const f32x4*)(W + (size_t)(n0 + r) * 512 + k0 + cc);
      s16x4 bp = { f2bf(b.x), f2bf(b.y), f2bf(b.z), f2bf(b.w) };
      *(s16x4*)(&Bs[r * LDT + cc]) = bp;
    }
    __syncthreads();

    s16x8 af[4], bfr[4];
    #pragma unroll
    for (int mf = 0; mf < 4; ++mf)
      af[mf] = *(const s16x8*)(&As[(wm + mf * 16 + tq) * LDT + quad * 8]);
    #pragma unroll
    for (int nf = 0; nf < 4; ++nf)
      bfr[nf] = *(const s16x8*)(&Bs[(wn + nf * 16 + tq) * LDT + quad * 8]);
    #pragma unroll
    for (int mf = 0; mf < 4; ++mf)
      #pragma unroll
      for (int nf = 0; nf < 4; ++nf)
        acc[mf][nf] = __builtin_amdgcn_mfma_f32_16x16x32_bf16(
            af[mf], bfr[nf], acc[mf][nf], 0, 0, 0);
    __syncthreads();
  }

  #pragma unroll
  for (int nf = 0; nf < 4; ++nf) {
    int col = n0 + wn + nf * 16 + tq;
    float bv = bi[col] + bh[col];
    #pragma unroll
    for (int mf = 0; mf < 4; ++mf) {
      #pragma unroll
      for (int r = 0; r < 4; ++r) {
        int row = m0 + wm + mf * 16 + quad * 4 + r;
        Out[(size_t)row * 512 + col] = acc[mf][nf][r] + bv;
      }
    }
  }
}

// ---------------------------------------------------------------------------
// Recurrence role. 1 WG = 1 batch, 512 threads, thread t = rg*8 + c:
// rows rg*8..+7, cols c*64..+63. Weights cols 0..47 in regs; cols 48..63
// streamed from the fp16 pack in GLOBAL (L2) each step via VMEM — the LDS
// pipe now carries only the h broadcast (8 x b128 + 1 write + 1 swizzle).
// wa/wb: two 8-load in-flight batches (32 regs each, never both at peak).
// Butterfly levels 1,2 via DPP quad_perm (VALU), level 3 via ds_swizzle.
// ---------------------------------------------------------------------------
__device__ void recur_role(char* smem, int b, int chunk,
                           float* __restrict__ xw_chunk,
                           const float* __restrict__ h0l,
                           const float* __restrict__ Wh,
                           const uint4* __restrict__ wgp,
                           float* __restrict__ hstate) {
  const int tid = threadIdx.x;
  const int c   = tid & 7;
  const int rg  = tid >> 3;
  _Float16* hbuf = (_Float16*)smem;    // [2][8*72]

  // preamble: 48 reg-resident cols (f32 load + pack, as before; no wlds)
  h2 wreg[8][24];
  #pragma unroll
  for (int k = 0; k < 8; ++k) {
    const float* wrow = Wh + (size_t)(rg * 8 + k) * H_ + c * 64;
    #pragma unroll
    for (int u = 0; u < 6; ++u) {
      f32x4 w4 = *(const f32x4*)(wrow + u * 8);
      f32x4 w5 = *(const f32x4*)(wrow + u * 8 + 4);
      wreg[k][u * 4 + 0] = h2{(_Float16)w4.x, (_Float16)w4.y};
      wreg[k][u * 4 + 1] = h2{(_Float16)w4.z, (_Float16)w4.w};
      wreg[k][u * 4 + 2] = h2{(_Float16)w5.x, (_Float16)w5.y};
      wreg[k][u * 4 + 3] = h2{(_Float16)w5.z, (_Float16)w5.w};
    }
  }

  float hini = (chunk == 0) ? h0l[b * H_ + tid] : hstate[b * H_ + tid];
  hbuf[(tid >> 6) * 72 + (tid & 63)] = (_Float16)hini;   // parity 0
  __syncthreads();

#define UBLK(HV, W0)                                                        \
  { h2 p0 = bch((HV).x), p1 = bch((HV).y), p2 = bch((HV).z), p3 = bch((HV).w); \
    _Pragma("unroll")                                                       \
    for (int k = 0; k < 8; ++k) {                                           \
      acc[k] = fdot2(wreg[k][(W0) + 0], p0, acc[k]);                        \
      acc[k] = fdot2(wreg[k][(W0) + 1], p1, acc[k]);                        \
      acc[k] = fdot2(wreg[k][(W0) + 2], p2, acc[k]);                        \
      acc[k] = fdot2(wreg[k][(W0) + 3], p3, acc[k]);                        \
    } }

#define SBLK(WARR, K0)                                                      \
  { h2 q0 = bch(hb.x), q1 = bch(hb.y), q2 = bch(hb.z), q3 = bch(hb.w);      \
    h2 r0 = bch(hx.x), r1 = bch(hx.y), r2 = bch(hx.z), r3 = bch(hx.w);      \
    _Pragma("unroll")                                                       \
    for (int k = 0; k < 4; ++k) {                                           \
      uint4 w0 = WARR[2 * k], w1 = WARR[2 * k + 1];                         \
      float a = acc[(K0) + k];                                              \
      a = fdot2(bch(w0.x), q0, a); a = fdot2(bch(w0.y), q1, a);             \
      a = fdot2(bch(w0.z), q2, a); a = fdot2(bch(w0.w), q3, a);             \
      a = fdot2(bch(w1.x), r0, a); a = fdot2(bch(w1.y), r1, a);             \
      a = fdot2(bch(w1.z), r2, a); a = fdot2(bch(w1.w), r3, a);             \
      acc[(K0) + k] = a;                                                    \
    } }

  float hlast = 0.f;
  for (int ls = 0; ls < CS; ++ls) {
    const int cur = ls & 1, nxt = cur ^ 1;
    float xwv = xw_chunk[(size_t)ls * BH + b * H_ + tid];

    // streamed-weight batch A (k rows 0..3): issue early, consume after u3
    uint4 wa[8];
    #pragma unroll
    for (int i = 0; i < 8; ++i) wa[i] = wgp[i * 512 + tid];

    const _Float16* hrow = &hbuf[cur * (8 * 72) + c * 72];
#define HLD(i) (*(const uint4*)(hrow + (i) * 8))

    float acc[8] = {0, 0, 0, 0, 0, 0, 0, 0};

    // rolling 3-deep h buffer (12 regs): ha/hb/hx
    uint4 ha = HLD(0), hb = HLD(1), hx = HLD(2);

    UBLK(ha, 0);   ha = HLD(3);      // cols  0..7
    UBLK(hb, 4);   hb = HLD(6);      // cols  8..15 ; prefetch cols 48..55
    UBLK(hx, 8);   hx = HLD(7);      // cols 16..23 ; prefetch cols 56..63
    UBLK(ha, 12);  ha = HLD(4);      // cols 24..31

    SBLK(wa, 0);                     // streamed rows k=0..3 (cols 48..63)

    // streamed-weight batch B (k rows 4..7): in flight across u4,u5
    uint4 wb[8];
    #pragma unroll
    for (int i = 0; i < 8; ++i) wb[i] = wgp[(8 + i) * 512 + tid];

    UBLK(ha, 16);  ha = HLD(5);      // cols 32..39
    UBLK(ha, 20);                    // cols 40..47

    SBLK(wb, 4);                     // streamed rows k=4..7 (cols 48..63)

    // butterfly: xor1/xor2 on DPP (VALU), xor4 via ds_swizzle
    float r1v[4];
    #pragma unroll
    for (int p = 0; p < 4; ++p) {
      float send = (c & 1) ? acc[2 * p] : acc[2 * p + 1];
      float recv = dpp_xor1(send);
      float keep = (c & 1) ? acc[2 * p + 1] : acc[2 * p];
      r1v[p] = keep + recv;
    }
    float r2v[2];
    #pragma unroll
    for (int p = 0; p < 2; ++p) {
      float send = (c & 2) ? r1v[2 * p] : r1v[2 * p + 1];
      float recv = dpp_xor2(send);
      float keep = (c & 2) ? r1v[2 * p + 1] : r1v[2 * p];
      r2v[p] = keep + recv;
    }
    {
      float send = (c & 4) ? r2v[0] : r2v[1];
      float recv = swz<0x101F>(send);
      float keep = (c & 4) ? r2v[1] : r2v[0];
      float dot  = keep + recv;              // full dot for row == tid

      float pre = dot + xwv;
      float e   = __expf(2.f * pre);         // tanh = 1 - 2/(e^{2x}+1)
      float hni = 1.f - 2.f / (e + 1.f);
      xw_chunk[(size_t)ls * BH + b * H_ + tid] = hni;
      hbuf[nxt * (8 * 72) + (tid >> 6) * 72 + (tid & 63)] = (_Float16)hni;
      hlast = hni;
    }
    __syncthreads();
#undef HLD
  }
  hstate[b * H_ + tid] = hlast;
#undef UBLK
#undef SBLK
}

// ---------------------------------------------------------------------------
// Pipeline stage s (depth-3 software pipeline over 8 time-chunks):
//   blocks   0..63  R1: recur layer-0, chunk s        (0 <= s <= 7)
//   blocks  64..127 R2: recur layer-1, chunk s-2      (2 <= s <= 9)
//   blocks 128..191 G1: gemm x@W1^T,  chunk s+1       (-1 <= s <= 6)
//   blocks 192..255 G2: gemm y1@W2^T, chunk s-1       (1 <= s <= 8)
// xw1/y1 lives in a 4-slot ring in ws (lifetime spans 3 stages: s+1,s,s-1
// are distinct mod 4); packed fp16 streamed weights live at ws+32MiB.
// Large static LDS keeps 1 block/CU so R blocks never share a CU.
// ---------------------------------------------------------------------------
__global__ __launch_bounds__(512, 1)
void stage(int s,
           const float* __restrict__ x, const float* __restrict__ h0,
           const float* __restrict__ Wih, const float* __restrict__ Whh,
           const float* __restrict__ bih, const float* __restrict__ bhh,
           float* __restrict__ ws, float* __restrict__ out) {
  __shared__ __align__(16) char smem[133376];
  const int role = blockIdx.x >> 6;
  const int rb   = blockIdx.x & 63;
  float* hn = out + (size_t)TBH;
  const uint4* wpk = (const uint4*)(ws + WPK_OFF);

  if (role == 0) {                    // R1
    int cc = s;
    if (cc < 0 || cc >= NC) return;
    recur_role(smem, rb, cc, ws + (size_t)(cc & 3) * CSZ, h0, Whh, wpk, hn);
  } else if (role == 1) {             // R2
    int cc = s - 2;
    if (cc < 0 || cc >= NC) return;
    recur_role(smem, rb, cc, out + (size_t)cc * CSZ, h0 + BH,
               Whh + (size_t)H_ * H_, wpk + WPK_U4L, hn + BH);
  } else if (role == 2) {             // G1
    int cc = s + 1;
    if (cc < 0 || cc >= NC) return;
    gemm_role(smem, rb, x + (size_t)cc * CSZ, Wih, bih, bhh,
              ws + (size_t)(cc & 3) * CSZ);
  } else {                            // G2
    int cc = s - 1;
    if (cc < 0 || cc >= NC) return;
    gemm_role(smem, rb, ws + (size_t)(cc & 3) * CSZ,
              Wih + (size_t)H_ * H_, bih + H_, bhh + H_,
              out + (size_t)cc * CSZ);
  }
}

// ---------------------------------------------------------------------------
extern "C" void kernel_launch(void* const* d_in, const int* in_sizes, int n_in,
                              void* d_out, int out_size, void* d_ws, size_t ws_size,
                              hipStream_t stream) {
  const float* x   = (const float*)d_in[0];
  const float* h0  = (const float*)d_in[1];
  const float* Wih = (const float*)d_in[2];
  const float* Whh = (const float*)d_in[3];
  const float* bih = (const float*)d_in[4];
  const float* bhh = (const float*)d_in[5];
  float* out = (float*)d_out;
  float* ws  = (float*)d_ws;    // 4-slot xw/y ring (32 MiB) + fp16 W pack (256 KiB)

  prepack<<<2, 512, 0, stream>>>(Whh, ws);
  for (int s = -1; s <= NC + 1; ++s)
    stage<<<256, 512, 0, stream>>>(s, x, h0, Wih, Whh, bih, bhh, ws, out);
}

// Round 2
// 1557.702 us; speedup vs baseline: 1.5734x; 1.5734x over previous
//
#include <hip/hip_runtime.h>
#include <stdint.h>

#define T_ 512
#define B_ 64
#define H_ 512
#define L_ 2
#define TBH (T_*B_*H_)   // 16777216
#define BH  (B_*H_)      // 32768
#define NC  8            // time chunks
#define CS  64           // steps per chunk
#define CROWS (CS*B_)    // 4096 rows of [T*B] per chunk

typedef float    f32x4 __attribute__((ext_vector_type(4)));
typedef short    s16x8 __attribute__((ext_vector_type(8)));
typedef short    s16x4 __attribute__((ext_vector_type(4)));
typedef _Float16 h2    __attribute__((ext_vector_type(2)));

static __device__ __forceinline__ short f2bf(float f) {
  uint32_t u = __float_as_uint(f);
  u = (u + 0x7fffu + ((u >> 16) & 1u)) >> 16;  // RNE
  return (short)u;
}

static __device__ __forceinline__ float fdot2(h2 a, h2 b, float c) {
#if __has_builtin(__builtin_amdgcn_fdot2)
  return __builtin_amdgcn_fdot2(a, b, c, false);
#else
  return c + (float)a[0] * (float)b[0] + (float)a[1] * (float)b[1];
#endif
}

template <int IMM>
static __device__ __forceinline__ float swz(float v) {
  return __int_as_float(__builtin_amdgcn_ds_swizzle(__float_as_int(v), IMM));
}

// DPP quad_perm cross-lane (VALU pipe, replaces ds_swizzle for xor1/xor2)
static __device__ __forceinline__ float dpp_xor1(float v) {
  return __int_as_float(__builtin_amdgcn_mov_dpp(__float_as_int(v), 0xB1, 0xF, 0xF, true));
}
static __device__ __forceinline__ float dpp_xor2(float v) {
  return __int_as_float(__builtin_amdgcn_mov_dpp(__float_as_int(v), 0x4E, 0xF, 0xF, true));
}

static __device__ __forceinline__ uint32_t pack2(float a, float b) {
  h2 p = { (_Float16)a, (_Float16)b };
  return __builtin_bit_cast(uint32_t, p);
}

static __device__ __forceinline__ h2 bch(uint32_t u) {
  return __builtin_bit_cast(h2, u);
}

// ---------------------------------------------------------------------------
// GEMM role (unchanged): 512 threads, 256x128 tile, 8 waves as 4Mx2N of 64x64.
// ---------------------------------------------------------------------------
__device__ void gemm_role(char* smem, int rb,
                          const float* __restrict__ In,
                          const float* __restrict__ W,
                          const float* __restrict__ bi,
                          const float* __restrict__ bh,
                          float* __restrict__ Out) {
  constexpr int LDT = 40;
  short* As = (short*)smem;              // 256 x LDT
  short* Bs = (short*)(smem + 256 * LDT * 2);  // 128 x LDT

  const int tid  = threadIdx.x;
  const int m0   = (rb >> 2) * 256;
  const int n0   = (rb & 3) * 128;
  const int wave = tid >> 6, lane = tid & 63;
  const int wm   = (wave >> 1) * 64;
  const int wn   = (wave & 1) * 64;
  const int quad = lane >> 4, tq = lane & 15;

  f32x4 acc[4][4] = {};

  for (int k0 = 0; k0 < 512; k0 += 32) {
    #pragma unroll
    for (int v = 0; v < 4; ++v) {
      int idx = v * 512 + tid;
      int r = idx >> 3, cc = (idx & 7) * 4;
      f32x4 a = *(const f32x4*)(In + (size_t)(m0 + r) * 512 + k0 + cc);
      s16x4 ap = { f2bf(a.x), f2bf(a.y), f2bf(a.z), f2bf(a.w) };
      *(s16x4*)(&As[r * LDT + cc]) = ap;
    }
    #pragma unroll
    for (int v = 0; v < 2; ++v) {
      int idx = v * 512 + tid;
      int r = idx >> 3, cc = (idx & 7) * 4;
      f32x4 b = *(const f32x4*)(W + (size_t)(n0 + r) * 512 + k0 + cc);
      s16x4 bp = { f2bf(b.x), f2bf(b.y), f2bf(b.z), f2bf(b.w) };
      *(s16x4*)(&Bs[r * LDT + cc]) = bp;
    }
    __syncthreads();

    s16x8 af[4], bfr[4];
    #pragma unroll
    for (int mf = 0; mf < 4; ++mf)
      af[mf] = *(const s16x8*)(&As[(wm + mf * 16 + tq) * LDT + quad * 8]);
    #pragma unroll
    for (int nf = 0; nf < 4; ++nf)
      bfr[nf] = *(const s16x8*)(&Bs[(wn + nf * 16 + tq) * LDT + quad * 8]);
    #pragma unroll
    for (int mf = 0; mf < 4; ++mf)
      #pragma unroll
      for (int nf = 0; nf < 4; ++nf)
        acc[mf][nf] = __builtin_amdgcn_mfma_f32_16x16x32_bf16(
            af[mf], bfr[nf], acc[mf][nf], 0, 0, 0);
    __syncthreads();
  }

  #pragma unroll
  for (int nf = 0; nf < 4; ++nf) {
    int col = n0 + wn + nf * 16 + tq;
    float bv = bi[col] + bh[col];
    #pragma unroll
    for (int mf = 0; mf < 4; ++mf) {
      #pragma unroll
      for (int r = 0; r < 4; ++r) {
        int row = m0 + wm + mf * 16 + quad * 4 + r;
        Out[(size_t)row * 512 + col] = acc[mf][nf][r] + bv;
      }
    }
  }
}

// ---------------------------------------------------------------------------
// Recurrence role (one chunk of CS steps). 1 WG = 1 batch, 512 threads.
// Thread t = rg*8 + c: rows rg*8..+7, column chunk c*64..+63.
// Weights: cols 0..47 in regs (compiler splits arch/AGPR), cols 48..63 in
// LDS ([row*2+part][tid] uint4). NEW vs r0: the 16 LDS weight reads are
// software-pipelined into the UBLK compute (batches of 4 b128 issued one
// UBLK ~128cy ahead of their consume) instead of JIT in a tail loop, and
// h cols 48..63 live in dedicated q4/r4 regs loaded once per step.
// Butterfly levels 1,2 on DPP quad_perm (VALU); level 3 via ds_swizzle.
// ---------------------------------------------------------------------------
__device__ void recur_role(char* smem, int b, int chunk,
                           float* __restrict__ xw_y,
                           const float* __restrict__ h0l,
                           const float* __restrict__ Wh,
                           float* __restrict__ hstate) {
  const int tid = threadIdx.x;
  const int c   = tid & 7;
  const int rg  = tid >> 3;

  uint4*    wlds = (uint4*)smem;                     // 16*512 entries, 128 KiB
  _Float16* hbuf = (_Float16*)(smem + 131072);       // [2][8*72]

  h2 wreg[8][24];
  #pragma unroll
  for (int k = 0; k < 8; ++k) {
    const float* wrow = Wh + (size_t)(rg * 8 + k) * 512 + c * 64;
    #pragma unroll
    for (int u = 0; u < 6; ++u) {
      f32x4 w4 = *(const f32x4*)(wrow + u * 8);
      f32x4 w5 = *(const f32x4*)(wrow + u * 8 + 4);
      wreg[k][u * 4 + 0] = h2{(_Float16)w4.x, (_Float16)w4.y};
      wreg[k][u * 4 + 1] = h2{(_Float16)w4.z, (_Float16)w4.w};
      wreg[k][u * 4 + 2] = h2{(_Float16)w5.x, (_Float16)w5.y};
      wreg[k][u * 4 + 3] = h2{(_Float16)w5.z, (_Float16)w5.w};
    }
    #pragma unroll
    for (int p = 0; p < 2; ++p) {
      f32x4 w4 = *(const f32x4*)(wrow + 48 + p * 8);
      f32x4 w5 = *(const f32x4*)(wrow + 48 + p * 8 + 4);
      uint4 pk;
      pk.x = pack2(w4.x, w4.y);
      pk.y = pack2(w4.z, w4.w);
      pk.z = pack2(w5.x, w5.y);
      pk.w = pack2(w5.z, w5.w);
      wlds[(k * 2 + p) * 512 + tid] = pk;
    }
  }

  float hini = (chunk == 0) ? h0l[b * 512 + tid] : hstate[b * 512 + tid];
  hbuf[(tid >> 6) * 72 + (tid & 63)] = (_Float16)hini;   // parity 0 (t0 even)
  __syncthreads();

#define UBLK(HV, W0)                                                        \
  { h2 p0 = bch((HV).x), p1 = bch((HV).y), p2 = bch((HV).z), p3 = bch((HV).w); \
    _Pragma("unroll")                                                       \
    for (int k = 0; k < 8; ++k) {                                           \
      acc[k] = fdot2(wreg[k][(W0) + 0], p0, acc[k]);                        \
      acc[k] = fdot2(wreg[k][(W0) + 1], p1, acc[k]);                        \
      acc[k] = fdot2(wreg[k][(W0) + 2], p2, acc[k]);                        \
      acc[k] = fdot2(wreg[k][(W0) + 3], p3, acc[k]);                        \
    } }

  // load one 2-row weight batch (k rows 2g, 2g+1): wlds indices 4g..4g+3
#define WLDX(g)                                                             \
  { wt0 = wlds[(4 * (g) + 0) * 512 + tid];                                  \
    wt1 = wlds[(4 * (g) + 1) * 512 + tid];                                  \
    wt2 = wlds[(4 * (g) + 2) * 512 + tid];                                  \
    wt3 = wlds[(4 * (g) + 3) * 512 + tid]; }

  // consume batch for acc[K0], acc[K0+1] using h cols 48..63 in q4/r4
#define CONSX(K0)                                                           \
  { h2 q0 = bch(q4.x), q1 = bch(q4.y), q2 = bch(q4.z), q3 = bch(q4.w);      \
    h2 r0 = bch(r4.x), r1 = bch(r4.y), r2 = bch(r4.z), r3 = bch(r4.w);      \
    float a = acc[(K0)];                                                    \
    a = fdot2(bch(wt0.x), q0, a); a = fdot2(bch(wt0.y), q1, a);             \
    a = fdot2(bch(wt0.z), q2, a); a = fdot2(bch(wt0.w), q3, a);             \
    a = fdot2(bch(wt1.x), r0, a); a = fdot2(bch(wt1.y), r1, a);             \
    a = fdot2(bch(wt1.z), r2, a); a = fdot2(bch(wt1.w), r3, a);             \
    acc[(K0)] = a;                                                          \
    a = acc[(K0) + 1];                                                      \
    a = fdot2(bch(wt2.x), q0, a); a = fdot2(bch(wt2.y), q1, a);             \
    a = fdot2(bch(wt2.z), q2, a); a = fdot2(bch(wt2.w), q3, a);             \
    a = fdot2(bch(wt3.x), r0, a); a = fdot2(bch(wt3.y), r1, a);             \
    a = fdot2(bch(wt3.z), r2, a); a = fdot2(bch(wt3.w), r3, a);             \
    acc[(K0) + 1] = a; }

  const int t0 = chunk * CS;
  float hlast = 0.f;
  for (int t = t0; t < t0 + CS; ++t) {
    const int cur = t & 1, nxt = cur ^ 1;
    float xwv = xw_y[(size_t)t * BH + b * 512 + tid];

    const _Float16* hc = &hbuf[cur * 8 * 72 + c * 72];
#define HLD(i) (*(const uint4*)(hc + (i) * 8))

    float acc[8] = {0, 0, 0, 0, 0, 0, 0, 0};

    // h: rolling 3-deep (ha/hbv/hx) for UBLKs; q4/r4 pinned (cols 48..63)
    uint4 ha = HLD(0), hbv = HLD(1), hx = HLD(2);
    uint4 q4 = HLD(6), r4 = HLD(7);
    uint4 wt0, wt1, wt2, wt3;

    WLDX(0);                         // k=0,1 in flight
    UBLK(ha, 0);   ha  = HLD(3);     // cols  0..7
    CONSX(0);      WLDX(1);          // consume k=0,1; issue k=2,3
    UBLK(hbv, 4);  hbv = HLD(4);     // cols  8..15
    CONSX(2);      WLDX(2);          // consume k=2,3; issue k=4,5
    UBLK(hx, 8);   hx  = HLD(5);     // cols 16..23
    CONSX(4);      WLDX(3);          // consume k=4,5; issue k=6,7
    UBLK(ha, 12);                    // cols 24..31
    CONSX(6);                        // consume k=6,7
    UBLK(hbv, 16);                   // cols 32..39
    UBLK(hx, 20);                    // cols 40..47

    // butterfly: xor1/xor2 on DPP (VALU), xor4 via ds_swizzle
    float r1v[4];
    #pragma unroll
    for (int p = 0; p < 4; ++p) {
      float send = (c & 1) ? acc[2 * p] : acc[2 * p + 1];
      float recv = dpp_xor1(send);
      float keep = (c & 1) ? acc[2 * p + 1] : acc[2 * p];
      r1v[p] = keep + recv;
    }
    float r2v[2];
    #pragma unroll
    for (int p = 0; p < 2; ++p) {
      float send = (c & 2) ? r1v[2 * p] : r1v[2 * p + 1];
      float recv = dpp_xor2(send);
      float keep = (c & 2) ? r1v[2 * p + 1] : r1v[2 * p];
      r2v[p] = keep + recv;
    }
    {
      float send = (c & 4) ? r2v[0] : r2v[1];
      float recv = swz<0x101F>(send);
      float keep = (c & 4) ? r2v[1] : r2v[0];
      float dot  = keep + recv;              // full dot for row == tid

      float pre = dot + xwv;
      float e   = __expf(2.f * pre);         // tanh = 1 - 2/(e^{2x}+1)
      float hni = 1.f - 2.f / (e + 1.f);
      xw_y[(size_t)t * BH + b * 512 + tid] = hni;
      hbuf[nxt * 8 * 72 + (tid >> 6) * 72 + (tid & 63)] = (_Float16)hni;
      hlast = hni;
    }
    __syncthreads();
#undef HLD
  }
  hstate[b * 512 + tid] = hlast;   // final chunk leaves h_n in place
#undef UBLK
#undef WLDX
#undef CONSX
}

// ---------------------------------------------------------------------------
// Pipeline stage s (depth-3 software pipeline over 8 time-chunks):
//   blocks   0..63  R1: recur layer-0, chunk s        (0 <= s <= 7)
//   blocks  64..127 R2: recur layer-1, chunk s-2      (2 <= s <= 9)
//   blocks 128..191 G1: gemm x@W1^T,  chunk s+1       (-1 <= s <= 6)
//   blocks 192..255 G2: gemm y1@W2^T, chunk s-1       (1 <= s <= 8)
// Launched for s = -1..9 (11 launches). Cross-launch visibility via stream
// ordering. h-states live in the hn output slots (final chunk = h_n).
// ---------------------------------------------------------------------------
__global__ __launch_bounds__(512, 1)
void stage(int s,
           const float* __restrict__ x, const float* __restrict__ h0,
           const float* __restrict__ Wih, const float* __restrict__ Whh,
           const float* __restrict__ bih, const float* __restrict__ bhh,
           float* __restrict__ ws, float* __restrict__ out) {
  __shared__ __align__(16) char smem[133376];  // 128K wlds + 2.25K hbuf
  const int role = blockIdx.x >> 6;
  const int rb   = blockIdx.x & 63;
  float* hn = out + (size_t)TBH;

  if (role == 0) {                    // R1
    int cc = s;
    if (cc < 0 || cc >= NC) return;
    recur_role(smem, rb, cc, ws, h0, Whh, hn);
  } else if (role == 1) {             // R2
    int cc = s - 2;
    if (cc < 0 || cc >= NC) return;
    recur_role(smem, rb, cc, out, h0 + BH, Whh + (size_t)H_ * H_, hn + BH);
  } else if (role == 2) {             // G1
    int cc = s + 1;
    if (cc < 0 || cc >= NC) return;
    gemm_role(smem, rb, x + (size_t)cc * CROWS * 512, Wih, bih, bhh,
              ws + (size_t)cc * CROWS * 512);
  } else {                            // G2
    int cc = s - 1;
    if (cc < 0 || cc >= NC) return;
    gemm_role(smem, rb, ws + (size_t)cc * CROWS * 512,
              Wih + (size_t)H_ * H_, bih + H_, bhh + H_,
              out + (size_t)cc * CROWS * 512);
  }
}

// ---------------------------------------------------------------------------
extern "C" void kernel_launch(void* const* d_in, const int* in_sizes, int n_in,
                              void* d_out, int out_size, void* d_ws, size_t ws_size,
                              hipStream_t stream) {
  const float* x   = (const float*)d_in[0];
  const float* h0  = (const float*)d_in[1];
  const float* Wih = (const float*)d_in[2];
  const float* Whh = (const float*)d_in[3];
  const float* bih = (const float*)d_in[4];
  const float* bhh = (const float*)d_in[5];
  float* out = (float*)d_out;
  float* ws  = (float*)d_ws;          // T*B*H*4 = 64 MiB (xw1/y1)

  for (int s = -1; s <= NC + 1; ++s)
    stage<<<256, 512, 0, stream>>>(s, x, h0, Wih, Whh, bih, bhh, ws, out);
}

// Round 4
// 1458.380 us; speedup vs baseline: 1.6805x; 1.0681x over previous
//
#include <hip/hip_runtime.h>
#include <stdint.h>

#define T_ 512
#define B_ 64
#define H_ 512
#define L_ 2
#define TBH (T_*B_*H_)   // 16777216
#define BH  (B_*H_)      // 32768
#define NC  8            // time chunks
#define CS  64           // steps per chunk
#define CROWS (CS*B_)    // 4096 rows of [T*B] per chunk

typedef float    f32x4 __attribute__((ext_vector_type(4)));
typedef short    s16x8 __attribute__((ext_vector_type(8)));
typedef short    s16x4 __attribute__((ext_vector_type(4)));
typedef _Float16 h2    __attribute__((ext_vector_type(2)));

static __device__ __forceinline__ short f2bf(float f) {
  uint32_t u = __float_as_uint(f);
  u = (u + 0x7fffu + ((u >> 16) & 1u)) >> 16;  // RNE
  return (short)u;
}

static __device__ __forceinline__ float fdot2(h2 a, h2 b, float c) {
#if __has_builtin(__builtin_amdgcn_fdot2)
  return __builtin_amdgcn_fdot2(a, b, c, false);
#else
  return c + (float)a[0] * (float)b[0] + (float)a[1] * (float)b[1];
#endif
}

template <int IMM>
static __device__ __forceinline__ float swz(float v) {
  return __int_as_float(__builtin_amdgcn_ds_swizzle(__float_as_int(v), IMM));
}

// DPP quad_perm cross-lane (VALU pipe): lane^1, lane^2
static __device__ __forceinline__ float dpp_xor1(float v) {
  return __int_as_float(__builtin_amdgcn_mov_dpp(__float_as_int(v), 0xB1, 0xF, 0xF, true));
}
static __device__ __forceinline__ float dpp_xor2(float v) {
  return __int_as_float(__builtin_amdgcn_mov_dpp(__float_as_int(v), 0x4E, 0xF, 0xF, true));
}

// Raw workgroup barrier WITHOUT the vmcnt(0) drain __syncthreads carries.
// LDS ordering guaranteed by the explicit lgkmcnt(0); sched_barrier(0)
// fences prevent hipcc hoisting memory ops across the inline asm (rule #18).
static __device__ __forceinline__ void rawbar() {
  __builtin_amdgcn_sched_barrier(0);
  asm volatile("s_waitcnt lgkmcnt(0)" ::: "memory");
  __builtin_amdgcn_s_barrier();
  __builtin_amdgcn_sched_barrier(0);
}

static __device__ __forceinline__ uint32_t pack2(float a, float b) {
  h2 p = { (_Float16)a, (_Float16)b };
  return __builtin_bit_cast(uint32_t, p);
}

static __device__ __forceinline__ h2 bch(uint32_t u) {
  return __builtin_bit_cast(h2, u);
}

// ---------------------------------------------------------------------------
// GEMM role (unchanged): 512 threads, 256x128 tile, 8 waves as 4Mx2N of 64x64.
// ---------------------------------------------------------------------------
__device__ void gemm_role(char* smem, int rb,
                          const float* __restrict__ In,
                          const float* __restrict__ W,
                          const float* __restrict__ bi,
                          const float* __restrict__ bh,
                          float* __restrict__ Out) {
  constexpr int LDT = 40;
  short* As = (short*)smem;              // 256 x LDT
  short* Bs = (short*)(smem + 256 * LDT * 2);  // 128 x LDT

  const int tid  = threadIdx.x;
  const int m0   = (rb >> 2) * 256;
  const int n0   = (rb & 3) * 128;
  const int wave = tid >> 6, lane = tid & 63;
  const int wm   = (wave >> 1) * 64;
  const int wn   = (wave & 1) * 64;
  const int quad = lane >> 4, tq = lane & 15;

  f32x4 acc[4][4] = {};

  for (int k0 = 0; k0 < 512; k0 += 32) {
    #pragma unroll
    for (int v = 0; v < 4; ++v) {
      int idx = v * 512 + tid;
      int r = idx >> 3, cc = (idx & 7) * 4;
      f32x4 a = *(const f32x4*)(In + (size_t)(m0 + r) * 512 + k0 + cc);
      s16x4 ap = { f2bf(a.x), f2bf(a.y), f2bf(a.z), f2bf(a.w) };
      *(s16x4*)(&As[r * LDT + cc]) = ap;
    }
    #pragma unroll
    for (int v = 0; v < 2; ++v) {
      int idx = v * 512 + tid;
      int r = idx >> 3, cc = (idx & 7) * 4;
      f32x4 b = *(const f32x4*)(W + (size_t)(n0 + r) * 512 + k0 + cc);
      s16x4 bp = { f2bf(b.x), f2bf(b.y), f2bf(b.z), f2bf(b.w) };
      *(s16x4*)(&Bs[r * LDT + cc]) = bp;
    }
    __syncthreads();

    s16x8 af[4], bfr[4];
    #pragma unroll
    for (int mf = 0; mf < 4; ++mf)
      af[mf] = *(const s16x8*)(&As[(wm + mf * 16 + tq) * LDT + quad * 8]);
    #pragma unroll
    for (int nf = 0; nf < 4; ++nf)
      bfr[nf] = *(const s16x8*)(&Bs[(wn + nf * 16 + tq) * LDT + quad * 8]);
    #pragma unroll
    for (int mf = 0; mf < 4; ++mf)
      #pragma unroll
      for (int nf = 0; nf < 4; ++nf)
        acc[mf][nf] = __builtin_amdgcn_mfma_f32_16x16x32_bf16(
            af[mf], bfr[nf], acc[mf][nf], 0, 0, 0);
    __syncthreads();
  }

  #pragma unroll
  for (int nf = 0; nf < 4; ++nf) {
    int col = n0 + wn + nf * 16 + tq;
    float bv = bi[col] + bh[col];
    #pragma unroll
    for (int mf = 0; mf < 4; ++mf) {
      #pragma unroll
      for (int r = 0; r < 4; ++r) {
        int row = m0 + wm + mf * 16 + quad * 4 + r;
        Out[(size_t)row * 512 + col] = acc[mf][nf][r] + bv;
      }
    }
  }
}

// ---------------------------------------------------------------------------
// Recurrence role (one chunk of CS steps). 1 WG = 1 batch, 512 threads.
// Thread t = rg*8 + c: rows rg*8..+7, column chunk c*64..+63.
// Weights: cols 0..47 in regs, cols 48..63 in LDS (pipelined WLDX/CONSX).
// r4: raw s_barrier + lgkmcnt(0) per step (no vmcnt(0) drain -> y global
// store stays in flight across steps); xw prefetched one step ahead;
// butterfly xor1/xor2 on DPP (VALU), xor4 via ds_swizzle (gfx950 has no
// permlane16 - that was r3's compile failure).
// ---------------------------------------------------------------------------
__device__ void recur_role(char* smem, int b, int chunk,
                           float* __restrict__ xw_y,
                           const float* __restrict__ h0l,
                           const float* __restrict__ Wh,
                           float* __restrict__ hstate) {
  const int tid = threadIdx.x;
  const int c   = tid & 7;
  const int rg  = tid >> 3;

  uint4*    wlds = (uint4*)smem;                     // 16*512 entries, 128 KiB
  _Float16* hbuf = (_Float16*)(smem + 131072);       // [2][8*72]

  h2 wreg[8][24];
  #pragma unroll
  for (int k = 0; k < 8; ++k) {
    const float* wrow = Wh + (size_t)(rg * 8 + k) * 512 + c * 64;
    #pragma unroll
    for (int u = 0; u < 6; ++u) {
      f32x4 w4 = *(const f32x4*)(wrow + u * 8);
      f32x4 w5 = *(const f32x4*)(wrow + u * 8 + 4);
      wreg[k][u * 4 + 0] = h2{(_Float16)w4.x, (_Float16)w4.y};
      wreg[k][u * 4 + 1] = h2{(_Float16)w4.z, (_Float16)w4.w};
      wreg[k][u * 4 + 2] = h2{(_Float16)w5.x, (_Float16)w5.y};
      wreg[k][u * 4 + 3] = h2{(_Float16)w5.z, (_Float16)w5.w};
    }
    #pragma unroll
    for (int p = 0; p < 2; ++p) {
      f32x4 w4 = *(const f32x4*)(wrow + 48 + p * 8);
      f32x4 w5 = *(const f32x4*)(wrow + 48 + p * 8 + 4);
      uint4 pk;
      pk.x = pack2(w4.x, w4.y);
      pk.y = pack2(w4.z, w4.w);
      pk.z = pack2(w5.x, w5.y);
      pk.w = pack2(w5.z, w5.w);
      wlds[(k * 2 + p) * 512 + tid] = pk;
    }
  }

  float hini = (chunk == 0) ? h0l[b * 512 + tid] : hstate[b * 512 + tid];
  hbuf[(tid >> 6) * 72 + (tid & 63)] = (_Float16)hini;   // parity 0 (t0 even)
  __syncthreads();

#define UBLK(HV, W0)                                                        \
  { h2 p0 = bch((HV).x), p1 = bch((HV).y), p2 = bch((HV).z), p3 = bch((HV).w); \
    _Pragma("unroll")                                                       \
    for (int k = 0; k < 8; ++k) {                                           \
      acc[k] = fdot2(wreg[k][(W0) + 0], p0, acc[k]);                        \
      acc[k] = fdot2(wreg[k][(W0) + 1], p1, acc[k]);                        \
      acc[k] = fdot2(wreg[k][(W0) + 2], p2, acc[k]);                        \
      acc[k] = fdot2(wreg[k][(W0) + 3], p3, acc[k]);                        \
    } }

#define WLDX(g)                                                             \
  { wt0 = wlds[(4 * (g) + 0) * 512 + tid];                                  \
    wt1 = wlds[(4 * (g) + 1) * 512 + tid];                                  \
    wt2 = wlds[(4 * (g) + 2) * 512 + tid];                                  \
    wt3 = wlds[(4 * (g) + 3) * 512 + tid]; }

#define CONSX(K0)                                                           \
  { h2 q0 = bch(q4.x), q1 = bch(q4.y), q2 = bch(q4.z), q3 = bch(q4.w);      \
    h2 r0 = bch(r4.x), r1 = bch(r4.y), r2 = bch(r4.z), r3 = bch(r4.w);      \
    float a = acc[(K0)];                                                    \
    a = fdot2(bch(wt0.x), q0, a); a = fdot2(bch(wt0.y), q1, a);             \
    a = fdot2(bch(wt0.z), q2, a); a = fdot2(bch(wt0.w), q3, a);             \
    a = fdot2(bch(wt1.x), r0, a); a = fdot2(bch(wt1.y), r1, a);             \
    a = fdot2(bch(wt1.z), r2, a); a = fdot2(bch(wt1.w), r3, a);             \
    acc[(K0)] = a;                                                          \
    a = acc[(K0) + 1];                                                      \
    a = fdot2(bch(wt2.x), q0, a); a = fdot2(bch(wt2.y), q1, a);             \
    a = fdot2(bch(wt2.z), q2, a); a = fdot2(bch(wt2.w), q3, a);             \
    a = fdot2(bch(wt3.x), r0, a); a = fdot2(bch(wt3.y), r1, a);             \
    a = fdot2(bch(wt3.z), r2, a); a = fdot2(bch(wt3.w), r3, a);             \
    acc[(K0) + 1] = a; }

  const int t0 = chunk * CS;
  const float* xwp = xw_y + (size_t)b * 512 + tid;
  float xwv = xwp[(size_t)t0 * BH];               // step-t0 value
  float hlast = 0.f;
  for (int t = t0; t < t0 + CS; ++t) {
    const int cur = t & 1, nxt = cur ^ 1;
    // prefetch next step's xw (clamped on last iter); rides across rawbar
    int tn = (t + 1 < t0 + CS) ? t + 1 : t;
    float xwn = xwp[(size_t)tn * BH];

    const _Float16* hc = &hbuf[cur * 8 * 72 + c * 72];
#define HLD(i) (*(const uint4*)(hc + (i) * 8))

    float acc[8] = {0, 0, 0, 0, 0, 0, 0, 0};

    uint4 ha = HLD(0), hbv = HLD(1), hx = HLD(2);
    uint4 q4 = HLD(6), r4 = HLD(7);
    uint4 wt0, wt1, wt2, wt3;

    WLDX(0);                         // k=0,1 in flight
    UBLK(ha, 0);   ha  = HLD(3);     // cols  0..7
    CONSX(0);      WLDX(1);          // consume k=0,1; issue k=2,3
    UBLK(hbv, 4);  hbv = HLD(4);     // cols  8..15
    CONSX(2);      WLDX(2);          // consume k=2,3; issue k=4,5
    UBLK(hx, 8);   hx  = HLD(5);     // cols 16..23
    CONSX(4);      WLDX(3);          // consume k=4,5; issue k=6,7
    UBLK(ha, 12);                    // cols 24..31
    CONSX(6);                        // consume k=6,7
    UBLK(hbv, 16);                   // cols 32..39
    UBLK(hx, 20);                    // cols 40..47

    // butterfly: xor1/xor2 on DPP (VALU), xor4 via ds_swizzle
    float r1v[4];
    #pragma unroll
    for (int p = 0; p < 4; ++p) {
      float send = (c & 1) ? acc[2 * p] : acc[2 * p + 1];
      float recv = dpp_xor1(send);
      float keep = (c & 1) ? acc[2 * p + 1] : acc[2 * p];
      r1v[p] = keep + recv;
    }
    float r2v[2];
    #pragma unroll
    for (int p = 0; p < 2; ++p) {
      float send = (c & 2) ? r1v[2 * p] : r1v[2 * p + 1];
      float recv = dpp_xor2(send);
      float keep = (c & 2) ? r1v[2 * p + 1] : r1v[2 * p];
      r2v[p] = keep + recv;
    }
    {
      float send = (c & 4) ? r2v[0] : r2v[1];
      float recv = swz<0x101F>(send);
      float keep = (c & 4) ? r2v[1] : r2v[0];
      float dot  = keep + recv;              // full dot for row == tid

      float pre = dot + xwv;
      float e   = __expf(2.f * pre);         // tanh = 1 - 2/(e^{2x}+1)
      float hni = 1.f - 2.f / (e + 1.f);
      xw_y[(size_t)t * BH + b * 512 + tid] = hni;
      hbuf[nxt * 8 * 72 + (tid >> 6) * 72 + (tid & 63)] = (_Float16)hni;
      hlast = hni;
    }
    rawbar();                        // lgkm-only barrier; y-store not drained
    xwv = xwn;
#undef HLD
  }
  hstate[b * 512 + tid] = hlast;   // final chunk leaves h_n in place
#undef UBLK
#undef WLDX
#undef CONSX
}

// ---------------------------------------------------------------------------
// Pipeline stage s (depth-3 software pipeline over 8 time-chunks):
//   blocks   0..63  R1: recur layer-0, chunk s        (0 <= s <= 7)
//   blocks  64..127 R2: recur layer-1, chunk s-2      (2 <= s <= 9)
//   blocks 128..191 G1: gemm x@W1^T,  chunk s+1       (-1 <= s <= 6)
//   blocks 192..255 G2: gemm y1@W2^T, chunk s-1       (1 <= s <= 8)
// Launched for s = -1..9 (11 launches). Cross-launch visibility via stream
// ordering. h-states live in the hn output slots (final chunk = h_n).
// ---------------------------------------------------------------------------
__global__ __launch_bounds__(512, 1)
void stage(int s,
           const float* __restrict__ x, const float* __restrict__ h0,
           const float* __restrict__ Wih, const float* __restrict__ Whh,
           const float* __restrict__ bih, const float* __restrict__ bhh,
           float* __restrict__ ws, float* __restrict__ out) {
  __shared__ __align__(16) char smem[133376];  // 128K wlds + 2.25K hbuf
  const int role = blockIdx.x >> 6;
  const int rb   = blockIdx.x & 63;
  float* hn = out + (size_t)TBH;

  if (role == 0) {                    // R1
    int cc = s;
    if (cc < 0 || cc >= NC) return;
    recur_role(smem, rb, cc, ws, h0, Whh, hn);
  } else if (role == 1) {             // R2
    int cc = s - 2;
    if (cc < 0 || cc >= NC) return;
    recur_role(smem, rb, cc, out, h0 + BH, Whh + (size_t)H_ * H_, hn + BH);
  } else if (role == 2) {             // G1
    int cc = s + 1;
    if (cc < 0 || cc >= NC) return;
    gemm_role(smem, rb, x + (size_t)cc * CROWS * 512, Wih, bih, bhh,
              ws + (size_t)cc * CROWS * 512);
  } else {                            // G2
    int cc = s - 1;
    if (cc < 0 || cc >= NC) return;
    gemm_role(smem, rb, ws + (size_t)cc * CROWS * 512,
              Wih + (size_t)H_ * H_, bih + H_, bhh + H_,
              out + (size_t)cc * CROWS * 512);
  }
}

// ---------------------------------------------------------------------------
extern "C" void kernel_launch(void* const* d_in, const int* in_sizes, int n_in,
                              void* d_out, int out_size, void* d_ws, size_t ws_size,
                              hipStream_t stream) {
  const float* x   = (const float*)d_in[0];
  const float* h0  = (const float*)d_in[1];
  const float* Wih = (const float*)d_in[2];
  const float* Whh = (const float*)d_in[3];
  const float* bih = (const float*)d_in[4];
  const float* bhh = (const float*)d_in[5];
  float* out = (float*)d_out;
  float* ws  = (float*)d_ws;          // T*B*H*4 = 64 MiB (xw1/y1)

  for (int s = -1; s <= NC + 1; ++s)
    stage<<<256, 512, 0, stream>>>(s, x, h0, Wih, Whh, bih, bhh, ws, out);
}